// Round 3
// baseline (98.495 us; speedup 1.0000x reference)
//
#include <hip/hip_runtime.h>
#include <math.h>

#define NS 512
#define DE 512
#define NCL 5
#define KSPLIT 16          // gemm K-split: 16 partials of K=32
#define PART_ELEMS (KSPLIT * NS * NS)

// ---------------------------------------------------------------------------
// K1: rn[r] = 1/max(||pred[r]||, 1e-8)  (wave per row, shuffle reduce)
//     Block 0 zeroes the global accumulators + ticket.
// ---------------------------------------------------------------------------
__global__ __launch_bounds__(256) void k_norm(const float* __restrict__ pred,
                                              float* __restrict__ rn,
                                              float* __restrict__ ctrl) {
    const int tid = threadIdx.x;
    if (blockIdx.x == 0 && tid == 0) { ctrl[0] = 0.0f; ctrl[1] = 0.0f; ctrl[2] = 0.0f; }
    const int w = tid >> 6, lane = tid & 63;
    const float4* p4 = (const float4*)pred;
#pragma unroll
    for (int rr = 0; rr < 2; rr++) {
        const int r = blockIdx.x * 8 + w * 2 + rr;
        float4 a = p4[r * (DE / 4) + lane];
        float4 b = p4[r * (DE / 4) + 64 + lane];
        float ss = a.x * a.x + a.y * a.y + a.z * a.z + a.w * a.w
                 + b.x * b.x + b.y * b.y + b.z * b.z + b.w * b.w;
#pragma unroll
        for (int m = 32; m >= 1; m >>= 1) ss += __shfl_xor(ss, m, 64);
        if (lane == 0) rn[r] = 1.0f / fmaxf(sqrtf(ss), 1e-8f);
    }
}

// ---------------------------------------------------------------------------
// K2: split-K Gram partials on RAW pred. grid (4,4,16), 128x128 tile, K=32
//     per block, 8x8 outputs per thread. XOR-swizzled float4 LDS slots:
//     slot' = slot ^ ((row>>3)&7)  -> A reads broadcast, B reads 2-way (free).
// ---------------------------------------------------------------------------
__global__ __launch_bounds__(256, 1) void k_gemm(const float* __restrict__ pred,
                                                 float* __restrict__ part) {
    __shared__ float4 As4[128][8];
    __shared__ float4 Bs4[128][8];

    const int tid = threadIdx.x;
    const int row0 = blockIdx.y * 128, col0 = blockIdx.x * 128;
    const int kz0 = blockIdx.z * 32;

    // stage: thread -> row lr, float4 slots sbase..sbase+3 (swizzled)
    const int lr = tid >> 1;
    const int sbase = (tid & 1) * 4;
    const int swz = (lr >> 3) & 7;
    const float4* gA = (const float4*)&pred[(row0 + lr) * DE + kz0];
    const float4* gB = (const float4*)&pred[(col0 + lr) * DE + kz0];
#pragma unroll
    for (int q = 0; q < 4; q++) {
        int s = sbase + q;
        As4[lr][s ^ swz] = gA[s];
        Bs4[lr][s ^ swz] = gB[s];
    }
    __syncthreads();

    const int tx = tid & 15, ty = tid >> 4;
    const int aswz = ty & 7, bswz = tx & 7;
    float acc[8][8] = {};

#pragma unroll
    for (int q = 0; q < 8; q++) {
        float4 b4[8];
#pragma unroll
        for (int c = 0; c < 8; c++) b4[c] = Bs4[tx * 8 + c][q ^ bswz];
#pragma unroll
        for (int rr = 0; rr < 2; rr++) {
            float4 a4[4];
#pragma unroll
            for (int r = 0; r < 4; r++) a4[r] = As4[ty * 8 + rr * 4 + r][q ^ aswz];
#pragma unroll
            for (int r = 0; r < 4; r++) {
#pragma unroll
                for (int c = 0; c < 8; c++) {
                    float v = acc[rr * 4 + r][c];
                    v = fmaf(a4[r].x, b4[c].x, v);
                    v = fmaf(a4[r].y, b4[c].y, v);
                    v = fmaf(a4[r].z, b4[c].z, v);
                    v = fmaf(a4[r].w, b4[c].w, v);
                    acc[rr * 4 + r][c] = v;
                }
            }
        }
    }

    float* op = part + (size_t)blockIdx.z * NS * NS;
#pragma unroll
    for (int m = 0; m < 8; m++) {
        float4 o0 = make_float4(acc[m][0], acc[m][1], acc[m][2], acc[m][3]);
        float4 o1 = make_float4(acc[m][4], acc[m][5], acc[m][6], acc[m][7]);
        float* dst = &op[(row0 + ty * 8 + m) * NS + col0 + tx * 8];
        *(float4*)dst = o0;
        *(float4*)(dst + 4) = o1;
    }
}

// ---------------------------------------------------------------------------
// K3: per-anchor loss + ticket finalize. Block i = anchor i.
//   cos_ij = (sum_z part_z[i,j]) * rn[i] * rn[j]
//   v[j] = cos + |cp_i-cp_j| (negatives) else -1e30
//   s[k] = sum_j relu(v[j]-cos_ik): 16 k-lanes x 16 j-chunks (j cached in VGPRs)
// ---------------------------------------------------------------------------
__global__ __launch_bounds__(256, 2) void k_loss(const float* __restrict__ part,
                                                 const float* __restrict__ rn,
                                                 const int* __restrict__ target,
                                                 const float* __restrict__ draw,
                                                 float* __restrict__ ctrl,
                                                 float* __restrict__ out) {
    const int i = blockIdx.x;
    const int tid = threadIdx.x;

    __shared__ float4 v4s[NS / 4];
    __shared__ float  ck[NS];
    __shared__ int    pk[NS];
    __shared__ float  spart[NS * 17];
    __shared__ float  redf[256];
    __shared__ int    redi[256];
    __shared__ unsigned int pcount;

    float* gsum = ctrl;
    unsigned int* gnz    = (unsigned int*)(ctrl + 1);
    unsigned int* ticket = (unsigned int*)(ctrl + 2);

    // ordinal class positions
    float cp[NCL];
    cp[0] = 0.0f;
#pragma unroll
    for (int c = 0; c < NCL - 1; c++) cp[c + 1] = cp[c] + log1pf(expf(draw[c]));
    const int ti = target[i];
    const float cpi = cp[ti];
    const float rni = rn[i];
    if (tid == 0) pcount = 0u;
    __syncthreads();

    // cos row: sum 16 partial rows (float2 per thread), scale by rn
    float2 g = make_float2(0.0f, 0.0f);
#pragma unroll
    for (int z = 0; z < KSPLIT; z++) {
        float2 t = ((const float2*)&part[(size_t)z * NS * NS + (size_t)i * NS])[tid];
        g.x += t.x; g.y += t.y;
    }
    const int j0 = tid * 2;
    float2 rnj = ((const float2*)rn)[tid];
    float c0 = g.x * rni * rnj.x;
    float c1 = g.y * rni * rnj.y;
    int tj0 = target[j0], tj1 = target[j0 + 1];
    bool n0 = (tj0 != ti), n1 = (tj1 != ti);
    ck[j0] = c0; ck[j0 + 1] = c1;
    float2 vv = make_float2(n0 ? (c0 + fabsf(cpi - cp[tj0])) : -1e30f,
                            n1 ? (c1 + fabsf(cpi - cp[tj1])) : -1e30f);
    ((float2*)v4s)[tid] = vv;
    int ncnt = (n0 ? 1 : 0) + (n1 ? 1 : 0);
    if (!n0 && j0 != i)     pk[atomicAdd(&pcount, 1u)] = j0;
    if (!n1 && j0 + 1 != i) pk[atomicAdd(&pcount, 1u)] = j0 + 1;

    redi[tid] = ncnt;
    __syncthreads();
    for (int s = 128; s > 0; s >>= 1) {
        if (tid < s) redi[tid] += redi[tid + s];
        __syncthreads();
    }
    const int negcount = redi[0];
    const unsigned int npos = pcount;
    __syncthreads();   // protect redi reuse

    // pass 1: (kl, jc) split; 32 j's cached in registers
    const int kl = tid & 15, jc = tid >> 4;
    float4 vj[8];
#pragma unroll
    for (int t = 0; t < 8; t++) vj[t] = v4s[jc * 8 + t];

    for (unsigned int p = kl; p < npos; p += 16) {
        const float ckp = ck[pk[p]];
        float s0 = 0.0f, s1 = 0.0f;
#pragma unroll
        for (int t = 0; t < 8; t++) {
            float4 w = vj[t];
            s0 += fmaxf(w.x - ckp, 0.0f) + fmaxf(w.y - ckp, 0.0f);
            s1 += fmaxf(w.z - ckp, 0.0f) + fmaxf(w.w - ckp, 0.0f);
        }
        spart[p * 17 + jc] = s0 + s1;
    }
    __syncthreads();

    // pass 2: assemble s[k], accumulate sum + nonzero count
    float ssum = 0.0f;
    int nzc = 0;
    for (unsigned int p = tid; p < npos; p += 256) {
        float s = 0.0f;
#pragma unroll
        for (int q = 0; q < 16; q++) s += spart[p * 17 + q];
        ssum += s;
        if (s != 0.0f) nzc++;
    }

    redf[tid] = ssum;
    redi[tid] = nzc;
    __syncthreads();
    for (int s = 128; s > 0; s >>= 1) {
        if (tid < s) { redf[tid] += redf[tid + s]; redi[tid] += redi[tid + s]; }
        __syncthreads();
    }
    if (tid == 0) {
        int denom = negcount > 1 ? negcount : 1;
        if (redf[0] != 0.0f || redi[0] != 0) {
            atomicAdd(gsum, redf[0] / (float)denom);
            atomicAdd(gnz, (unsigned int)redi[0]);
        }
        __threadfence();
        unsigned int t = atomicAdd(ticket, 1u);
        if (t == (unsigned int)(gridDim.x - 1)) {
            float s = atomicAdd(gsum, 0.0f);
            unsigned int n = atomicAdd(gnz, 0u);
            out[0] = s / (float)(n > 1u ? n : 1u);
        }
    }
}

extern "C" void kernel_launch(void* const* d_in, const int* in_sizes, int n_in,
                              void* d_out, int out_size, void* d_ws, size_t ws_size,
                              hipStream_t stream) {
    const float* pred   = (const float*)d_in[0];
    const float* draw   = (const float*)d_in[1];
    const int*   target = (const int*)d_in[2];
    float* out = (float*)d_out;

    float* ws   = (float*)d_ws;
    float* part = ws;                         // KSPLIT * 512*512 floats (16 MB)
    float* rn   = ws + PART_ELEMS;            // 512 floats
    float* ctrl = ws + PART_ELEMS + NS;       // gsum, gnz, ticket

    hipLaunchKernelGGL(k_norm, dim3(64), dim3(256), 0, stream, pred, rn, ctrl);
    hipLaunchKernelGGL(k_gemm, dim3(4, 4, KSPLIT), dim3(256), 0, stream, pred, part);
    hipLaunchKernelGGL(k_loss, dim3(NS), dim3(256), 0, stream,
                       part, rn, target, draw, ctrl, out);
}